// Round 1
// baseline (1351.173 us; speedup 1.0000x reference)
//
#include <hip/hip_runtime.h>
#include <cstdint>
#include <cstddef>

#define NFEAT 256
#define NHID 64
#define SLOPE 0.05f

// ---------------- K1: h = x @ W ; s = h@aw[:64] ; t = h@aw[64:] ----------------
// One wave per node. W (64 KB) staged in LDS; lane j owns h[n][j].
__global__ __launch_bounds__(256) void fc_kernel(
    const float* __restrict__ x, const float* __restrict__ W,
    const float* __restrict__ aw,
    float* __restrict__ h, float* __restrict__ s, float* __restrict__ t,
    int nNodes)
{
    __shared__ float Wl[NFEAT * NHID];
    const int tid = threadIdx.x;
    for (int i = tid * 4; i < NFEAT * NHID; i += 256 * 4)
        *(float4*)&Wl[i] = *(const float4*)&W[i];
    __syncthreads();

    const int lane = tid & 63;
    const int wv = tid >> 6;
    const float aws = aw[lane];
    const float awt = aw[64 + lane];
    const int stride = gridDim.x * 4;
    for (int n = blockIdx.x * 4 + wv; n < nNodes; n += stride) {
        const float* xr = x + (size_t)n * NFEAT;
        float acc = 0.f;
        #pragma unroll 8
        for (int k = 0; k < NFEAT; k += 4) {
            const float4 xv = *(const float4*)(xr + k);
            acc += xv.x * Wl[(k + 0) * NHID + lane];
            acc += xv.y * Wl[(k + 1) * NHID + lane];
            acc += xv.z * Wl[(k + 2) * NHID + lane];
            acc += xv.w * Wl[(k + 3) * NHID + lane];
        }
        h[(size_t)n * NHID + lane] = acc;
        float ps = acc * aws;
        float pt = acc * awt;
        #pragma unroll
        for (int off = 32; off > 0; off >>= 1) {
            ps += __shfl_xor(ps, off, 64);
            pt += __shfl_xor(pt, off, 64);
        }
        if (lane == 0) { s[n] = ps; t[n] = pt; }
    }
}

// ---------------- K2: histogram of src ----------------
__global__ __launch_bounds__(256) void hist_kernel(
    const int* __restrict__ ei, int E, int* __restrict__ count)
{
    int step = gridDim.x * blockDim.x;
    for (int e = blockIdx.x * blockDim.x + threadIdx.x; e < E; e += step)
        atomicAdd(&count[ei[e]], 1);
}

// ---------------- K3: exclusive scan (single block) ----------------
__global__ __launch_bounds__(256) void scan_kernel(
    const int* __restrict__ count, int* __restrict__ offsets,
    int* __restrict__ cursor, int nNodes)
{
    __shared__ int ssum[256];
    const int tid = threadIdx.x;
    const int seg = (nNodes + 255) / 256;
    const int b = tid * seg;
    const int e_ = min(b + seg, nNodes);
    int sum = 0;
    for (int i = b; i < e_; ++i) sum += count[i];
    ssum[tid] = sum;
    __syncthreads();
    if (tid == 0) {
        int run = 0;
        for (int i = 0; i < 256; ++i) { int v = ssum[i]; ssum[i] = run; run += v; }
    }
    __syncthreads();
    int run = ssum[tid];
    for (int i = b; i < e_; ++i) {
        offsets[i] = run; cursor[i] = run; run += count[i];
    }
    if (tid == 255) offsets[nNodes] = run;   // == E
}

// ---------------- K4: scatter edges into src-sorted order ----------------
__global__ __launch_bounds__(256) void scatter_kernel(
    const int* __restrict__ ei, int E, int* __restrict__ cursor,
    int* __restrict__ sdst, int* __restrict__ seid)
{
    int step = gridDim.x * blockDim.x;
    for (int e = blockIdx.x * blockDim.x + threadIdx.x; e < E; e += step) {
        int srcN = ei[e];
        int d = ei[E + e];
        int pos = atomicAdd(&cursor[srcN], 1);
        sdst[pos] = d;
        seid[pos] = e;
    }
}

// ---------------- K5: per-node softmax + aggregation (wave per node) ----------------
__global__ __launch_bounds__(256) void agg_kernel(
    const int* __restrict__ offsets, const int* __restrict__ sdst,
    const int* __restrict__ seid,
    const float* __restrict__ s, const float* __restrict__ t,
    const float* __restrict__ h, const float* __restrict__ ab_p,
    float* __restrict__ out, float* __restrict__ alpha, int nNodes)
{
    const int lane = threadIdx.x & 63;
    const int wv = threadIdx.x >> 6;
    const float ab = ab_p[0];
    const int stride = gridDim.x * 4;
    for (int n = blockIdx.x * 4 + wv; n < nNodes; n += stride) {
        const int beg = offsets[n];
        const int end = offsets[n + 1];
        const float sn = s[n];
        // pass 1: sum of exp over this node's edges (lane-parallel)
        float part = 0.f;
        for (int i = beg + lane; i < end; i += 64) {
            int d = sdst[i];
            float ev = sn + t[d] + ab;
            ev = (ev >= 0.f) ? ev : SLOPE * ev;
            part += __expf(ev);
        }
        #pragma unroll
        for (int off = 32; off > 0; off >>= 1)
            part += __shfl_xor(part, off, 64);
        const float inv = (end > beg) ? 1.0f / part : 0.f;
        // pass 2: alpha + weighted accumulation of h rows (whole wave per edge)
        float acc = 0.f;
        for (int i = beg; i < end; ++i) {
            int d = sdst[i];
            float ev = sn + t[d] + ab;
            ev = (ev >= 0.f) ? ev : SLOPE * ev;
            float a = __expf(ev) * inv;
            acc += a * h[(size_t)d * NHID + lane];
            if (lane == 0) alpha[seid[i]] = a;
        }
        out[(size_t)n * NHID + lane] = acc;
    }
}

extern "C" void kernel_launch(void* const* d_in, const int* in_sizes, int n_in,
                              void* d_out, int out_size, void* d_ws, size_t ws_size,
                              hipStream_t stream)
{
    const float* x  = (const float*)d_in[0];
    const int*   ei = (const int*)d_in[1];
    const float* W  = (const float*)d_in[2];
    const float* aw = (const float*)d_in[3];
    const float* ab = (const float*)d_in[4];

    const int nNodes = in_sizes[0] / NFEAT;     // 100000
    const int E      = in_sizes[1] / 2;         // 3200000

    float* out   = (float*)d_out;               // [nNodes*64]
    float* alpha = out + (size_t)nNodes * NHID; // [E]

    // workspace layout
    float* h       = (float*)d_ws;                         // nNodes*64
    float* s       = h + (size_t)nNodes * NHID;            // nNodes
    float* t       = s + nNodes;                           // nNodes
    int*   count   = (int*)(t + nNodes);                   // nNodes
    int*   offsets = count + nNodes;                       // nNodes+1 (pad to +4)
    int*   cursor  = offsets + nNodes + 4;                 // nNodes
    int*   sdst    = cursor + nNodes;                      // E
    int*   seid    = sdst + E;                             // E

    hipMemsetAsync(count, 0, (size_t)nNodes * sizeof(int), stream);

    fc_kernel<<<2048, 256, 0, stream>>>(x, W, aw, h, s, t, nNodes);
    hist_kernel<<<2048, 256, 0, stream>>>(ei, E, count);
    scan_kernel<<<1, 256, 0, stream>>>(count, offsets, cursor, nNodes);
    scatter_kernel<<<2048, 256, 0, stream>>>(ei, E, cursor, sdst, seid);
    agg_kernel<<<2048, 256, 0, stream>>>(offsets, sdst, seid, s, t, h, ab,
                                         out, alpha, nNodes);
}

// Round 2
// 546.716 us; speedup vs baseline: 2.4714x; 2.4714x over previous
//
#include <hip/hip_runtime.h>
#include <cstdint>
#include <cstddef>

#define NFEAT 256
#define NHID 64
#define SLOPE 0.05f

// ---------------- K1: h = x @ W ; s = h@aw[:64] ; t = h@aw[64:] ----------------
// One wave per 4 nodes (register-blocked so each LDS W-read feeds 4 FMAs).
__device__ __forceinline__ void reduce_st(float acc, int n, float aws, float awt,
                                          float* __restrict__ s, float* __restrict__ t,
                                          int lane) {
    float ps = acc * aws, pt = acc * awt;
    #pragma unroll
    for (int off = 32; off > 0; off >>= 1) {
        ps += __shfl_xor(ps, off, 64);
        pt += __shfl_xor(pt, off, 64);
    }
    if (lane == 0) { s[n] = ps; t[n] = pt; }
}

__global__ __launch_bounds__(256) void fc_kernel(
    const float* __restrict__ x, const float* __restrict__ W,
    const float* __restrict__ aw,
    float* __restrict__ h, float* __restrict__ s, float* __restrict__ t,
    int nNodes)
{
    __shared__ float Wl[NFEAT * NHID];
    const int tid = threadIdx.x;
    for (int i = tid * 4; i < NFEAT * NHID; i += 256 * 4)
        *(float4*)&Wl[i] = *(const float4*)&W[i];
    __syncthreads();

    const int lane = tid & 63;
    const int wv = tid >> 6;
    const float aws = aw[lane];
    const float awt = aw[64 + lane];
    const int waveId = blockIdx.x * 4 + wv;
    const int nWaves = gridDim.x * 4;
    const int nChunks = (nNodes + 3) >> 2;

    for (int c = waveId; c < nChunks; c += nWaves) {
        const int n0 = c * 4;
        if (n0 + 4 <= nNodes) {
            const float* xr0 = x + (size_t)n0 * NFEAT;
            const float* xr1 = xr0 + NFEAT;
            const float* xr2 = xr1 + NFEAT;
            const float* xr3 = xr2 + NFEAT;
            float a0 = 0.f, a1 = 0.f, a2 = 0.f, a3 = 0.f;
            #pragma unroll 4
            for (int k = 0; k < NFEAT; k += 4) {
                const float4 v0 = *(const float4*)(xr0 + k);
                const float4 v1 = *(const float4*)(xr1 + k);
                const float4 v2 = *(const float4*)(xr2 + k);
                const float4 v3 = *(const float4*)(xr3 + k);
                const float w0 = Wl[(k + 0) * NHID + lane];
                const float w1 = Wl[(k + 1) * NHID + lane];
                const float w2 = Wl[(k + 2) * NHID + lane];
                const float w3 = Wl[(k + 3) * NHID + lane];
                a0 += v0.x * w0 + v0.y * w1 + v0.z * w2 + v0.w * w3;
                a1 += v1.x * w0 + v1.y * w1 + v1.z * w2 + v1.w * w3;
                a2 += v2.x * w0 + v2.y * w1 + v2.z * w2 + v2.w * w3;
                a3 += v3.x * w0 + v3.y * w1 + v3.z * w2 + v3.w * w3;
            }
            h[(size_t)(n0 + 0) * NHID + lane] = a0;
            h[(size_t)(n0 + 1) * NHID + lane] = a1;
            h[(size_t)(n0 + 2) * NHID + lane] = a2;
            h[(size_t)(n0 + 3) * NHID + lane] = a3;
            reduce_st(a0, n0 + 0, aws, awt, s, t, lane);
            reduce_st(a1, n0 + 1, aws, awt, s, t, lane);
            reduce_st(a2, n0 + 2, aws, awt, s, t, lane);
            reduce_st(a3, n0 + 3, aws, awt, s, t, lane);
        } else {
            for (int n = n0; n < nNodes; ++n) {
                const float* xr = x + (size_t)n * NFEAT;
                float acc = 0.f;
                for (int k = 0; k < NFEAT; k += 4) {
                    const float4 xv = *(const float4*)(xr + k);
                    acc += xv.x * Wl[(k + 0) * NHID + lane];
                    acc += xv.y * Wl[(k + 1) * NHID + lane];
                    acc += xv.z * Wl[(k + 2) * NHID + lane];
                    acc += xv.w * Wl[(k + 3) * NHID + lane];
                }
                h[(size_t)n * NHID + lane] = acc;
                reduce_st(acc, n, aws, awt, s, t, lane);
            }
        }
    }
}

// ---------------- K2: histogram of src + per-edge rank ----------------
__global__ __launch_bounds__(256) void hist_kernel(
    const int* __restrict__ ei, int E, int* __restrict__ count,
    int* __restrict__ rank)
{
    int step = gridDim.x * blockDim.x;
    for (int e = blockIdx.x * blockDim.x + threadIdx.x; e < E; e += step)
        rank[e] = atomicAdd(&count[ei[e]], 1);
}

// ---------------- K3a/b/c: hierarchical exclusive scan ----------------
__global__ __launch_bounds__(256) void scanA_kernel(
    const int* __restrict__ count, int* __restrict__ bsum, int nNodes)
{
    __shared__ int sh[256];
    const int i = blockIdx.x * 256 + threadIdx.x;
    sh[threadIdx.x] = (i < nNodes) ? count[i] : 0;
    __syncthreads();
    #pragma unroll
    for (int off = 128; off > 0; off >>= 1) {
        if (threadIdx.x < off) sh[threadIdx.x] += sh[threadIdx.x + off];
        __syncthreads();
    }
    if (threadIdx.x == 0) bsum[blockIdx.x] = sh[0];
}

__global__ __launch_bounds__(256) void scanB_kernel(
    const int* __restrict__ bsum, int* __restrict__ bscan, int NB)
{
    __shared__ int sh[512];
    const int tid = threadIdx.x;
    sh[tid] = (tid < NB) ? bsum[tid] : 0;
    sh[256 + tid] = (256 + tid < NB) ? bsum[256 + tid] : 0;
    __syncthreads();
    if (tid == 0) {
        int run = 0;
        for (int i = 0; i < NB; ++i) { int v = sh[i]; sh[i] = run; run += v; }
    }
    __syncthreads();
    if (tid < NB) bscan[tid] = sh[tid];
    if (256 + tid < NB) bscan[256 + tid] = sh[256 + tid];
}

__global__ __launch_bounds__(256) void scanC_kernel(
    const int* __restrict__ count, const int* __restrict__ bscan,
    int* __restrict__ offsets, int nNodes)
{
    __shared__ int sh[256];
    const int tid = threadIdx.x;
    const int i = blockIdx.x * 256 + tid;
    const int v = (i < nNodes) ? count[i] : 0;
    sh[tid] = v;
    __syncthreads();
    #pragma unroll
    for (int off = 1; off < 256; off <<= 1) {
        int add = (tid >= off) ? sh[tid - off] : 0;
        __syncthreads();
        sh[tid] += add;
        __syncthreads();
    }
    const int incl = sh[tid];
    const int base = bscan[blockIdx.x];
    if (i < nNodes) offsets[i] = base + incl - v;
    if (i == nNodes - 1) offsets[nNodes] = base + incl;   // == E
}

// ---------------- K4: scatter dst into src-sorted order (no atomics) ----------------
__global__ __launch_bounds__(256) void scatter_kernel(
    const int* __restrict__ ei, const int* __restrict__ rank,
    const int* __restrict__ offsets, int E, int* __restrict__ sdst)
{
    int step = gridDim.x * blockDim.x;
    for (int e = blockIdx.x * blockDim.x + threadIdx.x; e < E; e += step)
        sdst[offsets[ei[e]] + rank[e]] = ei[E + e];
}

// ---------------- K5: per-node aggregation, single unnormalized pass ----------------
// Wave per node. Chunk of 64 edges: each lane computes exp for its own edge
// (parallel), then shfl-broadcast inner loop unrolled x4 for MLP on h-row gathers.
__global__ __launch_bounds__(256) void agg_kernel(
    const int* __restrict__ offsets, const int* __restrict__ sdst,
    const float* __restrict__ s, const float* __restrict__ t,
    const float* __restrict__ h, const float* __restrict__ ab_p,
    float* __restrict__ out, float* __restrict__ rinv, int nNodes)
{
    const int lane = threadIdx.x & 63;
    const int wv = threadIdx.x >> 6;
    const float ab = ab_p[0];
    const int stride = gridDim.x * 4;
    for (int n = blockIdx.x * 4 + wv; n < nNodes; n += stride) {
        const int beg = offsets[n];
        const int end = offsets[n + 1];
        const float sn = s[n];
        float part = 0.f;
        float acc = 0.f;
        for (int i0 = beg; i0 < end; i0 += 64) {
            const int my = min(end - i0, 64);
            int dl = 0; float el = 0.f;
            if (lane < my) {
                dl = sdst[i0 + lane];
                float ev = sn + t[dl] + ab;
                ev = (ev >= 0.f) ? ev : SLOPE * ev;
                el = __expf(ev);
            }
            part += el;
            int j = 0;
            for (; j + 4 <= my; j += 4) {
                const int d0 = __shfl(dl, j);     const float e0 = __shfl(el, j);
                const int d1 = __shfl(dl, j + 1); const float e1 = __shfl(el, j + 1);
                const int d2 = __shfl(dl, j + 2); const float e2 = __shfl(el, j + 2);
                const int d3 = __shfl(dl, j + 3); const float e3 = __shfl(el, j + 3);
                const float h0 = h[(size_t)d0 * NHID + lane];
                const float h1 = h[(size_t)d1 * NHID + lane];
                const float h2 = h[(size_t)d2 * NHID + lane];
                const float h3 = h[(size_t)d3 * NHID + lane];
                acc += e0 * h0;
                acc += e1 * h1;
                acc += e2 * h2;
                acc += e3 * h3;
            }
            for (; j < my; ++j) {
                const int d0 = __shfl(dl, j);
                const float e0 = __shfl(el, j);
                acc += e0 * h[(size_t)d0 * NHID + lane];
            }
        }
        #pragma unroll
        for (int off = 32; off > 0; off >>= 1) part += __shfl_xor(part, off, 64);
        const float inv = (end > beg) ? 1.0f / part : 0.f;
        if (lane == 0) rinv[n] = inv;
        out[(size_t)n * NHID + lane] = acc * inv;
    }
}

// ---------------- K6: edge-parallel alpha (coalesced write) ----------------
__global__ __launch_bounds__(256) void alpha_kernel(
    const int* __restrict__ ei, const float* __restrict__ s,
    const float* __restrict__ t, const float* __restrict__ rinv,
    const float* __restrict__ ab_p, float* __restrict__ alpha, int E)
{
    const float ab = ab_p[0];
    int step = gridDim.x * blockDim.x;
    for (int e = blockIdx.x * blockDim.x + threadIdx.x; e < E; e += step) {
        const int sn = ei[e];
        const int d = ei[E + e];
        float ev = s[sn] + t[d] + ab;
        ev = (ev >= 0.f) ? ev : SLOPE * ev;
        alpha[e] = __expf(ev) * rinv[sn];
    }
}

extern "C" void kernel_launch(void* const* d_in, const int* in_sizes, int n_in,
                              void* d_out, int out_size, void* d_ws, size_t ws_size,
                              hipStream_t stream)
{
    const float* x  = (const float*)d_in[0];
    const int*   ei = (const int*)d_in[1];
    const float* W  = (const float*)d_in[2];
    const float* aw = (const float*)d_in[3];
    const float* ab = (const float*)d_in[4];

    const int nNodes = in_sizes[0] / NFEAT;     // 100000
    const int E      = in_sizes[1] / 2;         // 3200000
    const int NB     = (nNodes + 255) / 256;    // 391

    float* out   = (float*)d_out;               // [nNodes*64]
    float* alpha = out + (size_t)nNodes * NHID; // [E]

    // workspace layout
    float* h       = (float*)d_ws;                         // nNodes*64
    float* s       = h + (size_t)nNodes * NHID;            // nNodes
    float* t       = s + nNodes;                           // nNodes
    float* rinv    = t + nNodes;                           // nNodes
    int*   count   = (int*)(rinv + nNodes);                // nNodes
    int*   offsets = count + nNodes;                       // nNodes+1 (+pad)
    int*   bsum    = offsets + nNodes + 4;                 // NB
    int*   bscan   = bsum + NB;                            // NB
    int*   rank    = bscan + NB;                           // E
    int*   sdst    = rank + E;                             // E

    hipMemsetAsync(count, 0, (size_t)nNodes * sizeof(int), stream);

    fc_kernel<<<2048, 256, 0, stream>>>(x, W, aw, h, s, t, nNodes);
    hist_kernel<<<2048, 256, 0, stream>>>(ei, E, count, rank);
    scanA_kernel<<<NB, 256, 0, stream>>>(count, bsum, nNodes);
    scanB_kernel<<<1, 256, 0, stream>>>(bsum, bscan, NB);
    scanC_kernel<<<NB, 256, 0, stream>>>(count, bscan, offsets, nNodes);
    scatter_kernel<<<2048, 256, 0, stream>>>(ei, rank, offsets, E, sdst);
    agg_kernel<<<2048, 256, 0, stream>>>(offsets, sdst, s, t, h, ab,
                                         out, rinv, nNodes);
    alpha_kernel<<<2048, 256, 0, stream>>>(ei, s, t, rinv, ab, alpha, E);
}

// Round 4
// 406.079 us; speedup vs baseline: 3.3274x; 1.3463x over previous
//
#include <hip/hip_runtime.h>
#include <cstdint>
#include <cstddef>

#define NFEAT 256
#define NHID 64
#define SLOPE 0.05f
#define KC 64
#define TM 64

// ---------------- K1: h = x @ W ; s = h@aw[:64] ; t = h@aw[64:] ----------------
// Tiled fp32 GEMM: block = 64 nodes x 64 hid, K chunked x64.
// xT (transposed, pad 65) double-buffered; W chunk single-buffered.
// Thread (ny,jx) computes 4x4 register tile. Software-pipelined staging.
// NOTE: W chunk = 4096 floats = 16 floats/thread (4x float4) — R3's bug was
// staging only 1/4 of it.
__global__ __launch_bounds__(256, 3) void fc_kernel(
    const float* __restrict__ x, const float* __restrict__ W,
    const float* __restrict__ aw,
    float* __restrict__ h, float* __restrict__ s, float* __restrict__ t,
    int nNodes)
{
    __shared__ float xT[2][KC][TM + 1];   // 33280 B
    __shared__ float Wl[KC][NHID];        // 16384 B

    const int tid  = threadIdx.x;
    const int l    = tid & 63;
    const int w    = tid >> 6;
    const int jx4  = (tid & 15) * 4;      // hid col group
    const int ny4  = (tid >> 4) * 4;      // node group (0..60)
    const int n0   = blockIdx.x * TM;
    const int lrow = w * 16 + (l >> 4);   // staging row base (+ it*4)
    const int lkp  = (l & 15) * 4;        // staging k pos
    const int nClamp = nNodes - 1;

    float4 xr0, xr1, xr2, xr3;
    float4 wr0, wr1, wr2, wr3;

    #define LOADX(c) do {                                                   \
        const size_t kb = (size_t)(c) * KC + lkp;                           \
        const int r0 = min(n0 + lrow,      nClamp);                         \
        const int r1 = min(n0 + lrow + 4,  nClamp);                         \
        const int r2 = min(n0 + lrow + 8,  nClamp);                         \
        const int r3 = min(n0 + lrow + 12, nClamp);                         \
        xr0 = *(const float4*)&x[(size_t)r0 * NFEAT + kb];                  \
        xr1 = *(const float4*)&x[(size_t)r1 * NFEAT + kb];                  \
        xr2 = *(const float4*)&x[(size_t)r2 * NFEAT + kb];                  \
        xr3 = *(const float4*)&x[(size_t)r3 * NFEAT + kb];                  \
    } while (0)

    #define LOADW(c) do {                                                   \
        const float* Wc = W + (size_t)(c) * (KC * NHID);                    \
        wr0 = *(const float4*)&Wc[tid * 4];                                 \
        wr1 = *(const float4*)&Wc[tid * 4 + 1024];                          \
        wr2 = *(const float4*)&Wc[tid * 4 + 2048];                          \
        wr3 = *(const float4*)&Wc[tid * 4 + 3072];                          \
    } while (0)

    #define STOREX(b) do {                                                  \
        xT[b][lkp + 0][lrow + 0]  = xr0.x;                                  \
        xT[b][lkp + 1][lrow + 0]  = xr0.y;                                  \
        xT[b][lkp + 2][lrow + 0]  = xr0.z;                                  \
        xT[b][lkp + 3][lrow + 0]  = xr0.w;                                  \
        xT[b][lkp + 0][lrow + 4]  = xr1.x;                                  \
        xT[b][lkp + 1][lrow + 4]  = xr1.y;                                  \
        xT[b][lkp + 2][lrow + 4]  = xr1.z;                                  \
        xT[b][lkp + 3][lrow + 4]  = xr1.w;                                  \
        xT[b][lkp + 0][lrow + 8]  = xr2.x;                                  \
        xT[b][lkp + 1][lrow + 8]  = xr2.y;                                  \
        xT[b][lkp + 2][lrow + 8]  = xr2.z;                                  \
        xT[b][lkp + 3][lrow + 8]  = xr2.w;                                  \
        xT[b][lkp + 0][lrow + 12] = xr3.x;                                  \
        xT[b][lkp + 1][lrow + 12] = xr3.y;                                  \
        xT[b][lkp + 2][lrow + 12] = xr3.z;                                  \
        xT[b][lkp + 3][lrow + 12] = xr3.w;                                  \
    } while (0)

    #define STOREW() do {                                                   \
        float4* wp = (float4*)&Wl[0][0];                                    \
        wp[tid]       = wr0;                                                \
        wp[tid + 256] = wr1;                                                \
        wp[tid + 512] = wr2;                                                \
        wp[tid + 768] = wr3;                                                \
    } while (0)

    float4 a0 = {0.f,0.f,0.f,0.f}, a1 = a0, a2 = a0, a3 = a0;

    LOADX(0); LOADW(0);
    STOREX(0); STOREW();
    __syncthreads();

    for (int c = 0; c < NFEAT / KC; ++c) {
        const int b = c & 1;
        if (c < NFEAT / KC - 1) { LOADX(c + 1); LOADW(c + 1); }
        #pragma unroll 4
        for (int k = 0; k < KC; ++k) {
            const float4 wf = *(const float4*)&Wl[k][jx4];
            const float x0 = xT[b][k][ny4 + 0];
            const float x1 = xT[b][k][ny4 + 1];
            const float x2 = xT[b][k][ny4 + 2];
            const float x3 = xT[b][k][ny4 + 3];
            a0.x += x0 * wf.x; a0.y += x0 * wf.y; a0.z += x0 * wf.z; a0.w += x0 * wf.w;
            a1.x += x1 * wf.x; a1.y += x1 * wf.y; a1.z += x1 * wf.z; a1.w += x1 * wf.w;
            a2.x += x2 * wf.x; a2.y += x2 * wf.y; a2.z += x2 * wf.z; a2.w += x2 * wf.w;
            a3.x += x3 * wf.x; a3.y += x3 * wf.y; a3.z += x3 * wf.z; a3.w += x3 * wf.w;
        }
        if (c < NFEAT / KC - 1) {
            STOREX(b ^ 1);
            __syncthreads();      // all waves done reading Wl (and prior xT buf)
            STOREW();
            __syncthreads();      // staged data visible
        }
    }

    // epilogue: store h tile + fused s,t
    const float4 awsv = *(const float4*)&aw[jx4];
    const float4 awtv = *(const float4*)&aw[NHID + jx4];

    #define EPI(ar, r) do {                                                 \
        const int n = n0 + ny4 + (r);                                       \
        if (n < nNodes) *(float4*)&h[(size_t)n * NHID + jx4] = ar;          \
        float ps = ar.x*awsv.x + ar.y*awsv.y + ar.z*awsv.z + ar.w*awsv.w;   \
        float pt = ar.x*awtv.x + ar.y*awtv.y + ar.z*awtv.z + ar.w*awtv.w;   \
        ps += __shfl_xor(ps, 1, 16); pt += __shfl_xor(pt, 1, 16);           \
        ps += __shfl_xor(ps, 2, 16); pt += __shfl_xor(pt, 2, 16);           \
        ps += __shfl_xor(ps, 4, 16); pt += __shfl_xor(pt, 4, 16);           \
        ps += __shfl_xor(ps, 8, 16); pt += __shfl_xor(pt, 8, 16);           \
        if ((tid & 15) == 0 && n < nNodes) { s[n] = ps; t[n] = pt; }        \
    } while (0)

    EPI(a0, 0);
    EPI(a1, 1);
    EPI(a2, 2);
    EPI(a3, 3);
}

// ---------------- K2: histogram of src + per-edge rank ----------------
__global__ __launch_bounds__(256) void hist_kernel(
    const int* __restrict__ ei, int E, int* __restrict__ count,
    int* __restrict__ rank)
{
    int step = gridDim.x * blockDim.x;
    for (int e = blockIdx.x * blockDim.x + threadIdx.x; e < E; e += step)
        rank[e] = atomicAdd(&count[ei[e]], 1);
}

// ---------------- K3a/b/c: hierarchical exclusive scan ----------------
__global__ __launch_bounds__(256) void scanA_kernel(
    const int* __restrict__ count, int* __restrict__ bsum, int nNodes)
{
    __shared__ int sh[256];
    const int i = blockIdx.x * 256 + threadIdx.x;
    sh[threadIdx.x] = (i < nNodes) ? count[i] : 0;
    __syncthreads();
    #pragma unroll
    for (int off = 128; off > 0; off >>= 1) {
        if (threadIdx.x < off) sh[threadIdx.x] += sh[threadIdx.x + off];
        __syncthreads();
    }
    if (threadIdx.x == 0) bsum[blockIdx.x] = sh[0];
}

__global__ __launch_bounds__(256) void scanB_kernel(
    const int* __restrict__ bsum, int* __restrict__ bscan, int NB)
{
    __shared__ int sh[512];
    const int tid = threadIdx.x;
    sh[tid] = (tid < NB) ? bsum[tid] : 0;
    sh[256 + tid] = (256 + tid < NB) ? bsum[256 + tid] : 0;
    __syncthreads();
    if (tid == 0) {
        int run = 0;
        for (int i = 0; i < NB; ++i) { int v = sh[i]; sh[i] = run; run += v; }
    }
    __syncthreads();
    if (tid < NB) bscan[tid] = sh[tid];
    if (256 + tid < NB) bscan[256 + tid] = sh[256 + tid];
}

__global__ __launch_bounds__(256) void scanC_kernel(
    const int* __restrict__ count, const int* __restrict__ bscan,
    int* __restrict__ offsets, int nNodes)
{
    __shared__ int sh[256];
    const int tid = threadIdx.x;
    const int i = blockIdx.x * 256 + tid;
    const int v = (i < nNodes) ? count[i] : 0;
    sh[tid] = v;
    __syncthreads();
    #pragma unroll
    for (int off = 1; off < 256; off <<= 1) {
        int add = (tid >= off) ? sh[tid - off] : 0;
        __syncthreads();
        sh[tid] += add;
        __syncthreads();
    }
    const int incl = sh[tid];
    const int base = bscan[blockIdx.x];
    if (i < nNodes) offsets[i] = base + incl - v;
    if (i == nNodes - 1) offsets[nNodes] = base + incl;   // == E
}

// ---------------- K4: scatter dst into src-sorted order (no atomics) ----------------
__global__ __launch_bounds__(256) void scatter_kernel(
    const int* __restrict__ ei, const int* __restrict__ rank,
    const int* __restrict__ offsets, int E, int* __restrict__ sdst)
{
    int step = gridDim.x * blockDim.x;
    for (int e = blockIdx.x * blockDim.x + threadIdx.x; e < E; e += step)
        sdst[offsets[ei[e]] + rank[e]] = ei[E + e];
}

// ---------------- K5: per-node aggregation, single unnormalized pass ----------------
__global__ __launch_bounds__(256) void agg_kernel(
    const int* __restrict__ offsets, const int* __restrict__ sdst,
    const float* __restrict__ s, const float* __restrict__ t,
    const float* __restrict__ h, const float* __restrict__ ab_p,
    float* __restrict__ out, float* __restrict__ rinv, int nNodes)
{
    const int lane = threadIdx.x & 63;
    const int wv = threadIdx.x >> 6;
    const float ab = ab_p[0];
    const int stride = gridDim.x * 4;
    for (int n = blockIdx.x * 4 + wv; n < nNodes; n += stride) {
        const int beg = offsets[n];
        const int end = offsets[n + 1];
        const float sn = s[n];
        float part = 0.f;
        float acc = 0.f;
        for (int i0 = beg; i0 < end; i0 += 64) {
            const int my = min(end - i0, 64);
            int dl = 0; float el = 0.f;
            if (lane < my) {
                dl = sdst[i0 + lane];
                float ev = sn + t[dl] + ab;
                ev = (ev >= 0.f) ? ev : SLOPE * ev;
                el = __expf(ev);
            }
            part += el;
            int j = 0;
            for (; j + 4 <= my; j += 4) {
                const int d0 = __shfl(dl, j);     const float e0 = __shfl(el, j);
                const int d1 = __shfl(dl, j + 1); const float e1 = __shfl(el, j + 1);
                const int d2 = __shfl(dl, j + 2); const float e2 = __shfl(el, j + 2);
                const int d3 = __shfl(dl, j + 3); const float e3 = __shfl(el, j + 3);
                const float h0 = h[(size_t)d0 * NHID + lane];
                const float h1 = h[(size_t)d1 * NHID + lane];
                const float h2 = h[(size_t)d2 * NHID + lane];
                const float h3 = h[(size_t)d3 * NHID + lane];
                acc += e0 * h0;
                acc += e1 * h1;
                acc += e2 * h2;
                acc += e3 * h3;
            }
            for (; j < my; ++j) {
                const int d0 = __shfl(dl, j);
                const float e0 = __shfl(el, j);
                acc += e0 * h[(size_t)d0 * NHID + lane];
            }
        }
        #pragma unroll
        for (int off = 32; off > 0; off >>= 1) part += __shfl_xor(part, off, 64);
        const float inv = (end > beg) ? 1.0f / part : 0.f;
        if (lane == 0) rinv[n] = inv;
        out[(size_t)n * NHID + lane] = acc * inv;
    }
}

// ---------------- K6: edge-parallel alpha (coalesced write) ----------------
__global__ __launch_bounds__(256) void alpha_kernel(
    const int* __restrict__ ei, const float* __restrict__ s,
    const float* __restrict__ t, const float* __restrict__ rinv,
    const float* __restrict__ ab_p, float* __restrict__ alpha, int E)
{
    const float ab = ab_p[0];
    int step = gridDim.x * blockDim.x;
    for (int e = blockIdx.x * blockDim.x + threadIdx.x; e < E; e += step) {
        const int sn = ei[e];
        const int d = ei[E + e];
        float ev = s[sn] + t[d] + ab;
        ev = (ev >= 0.f) ? ev : SLOPE * ev;
        alpha[e] = __expf(ev) * rinv[sn];
    }
}

extern "C" void kernel_launch(void* const* d_in, const int* in_sizes, int n_in,
                              void* d_out, int out_size, void* d_ws, size_t ws_size,
                              hipStream_t stream)
{
    const float* x  = (const float*)d_in[0];
    const int*   ei = (const int*)d_in[1];
    const float* W  = (const float*)d_in[2];
    const float* aw = (const float*)d_in[3];
    const float* ab = (const float*)d_in[4];

    const int nNodes = in_sizes[0] / NFEAT;     // 100000
    const int E      = in_sizes[1] / 2;         // 3200000
    const int NB     = (nNodes + 255) / 256;    // 391
    const int NBfc   = (nNodes + TM - 1) / TM;  // 1563

    float* out   = (float*)d_out;               // [nNodes*64]
    float* alpha = out + (size_t)nNodes * NHID; // [E]

    // workspace layout
    float* h       = (float*)d_ws;                         // nNodes*64
    float* s       = h + (size_t)nNodes * NHID;            // nNodes
    float* t       = s + nNodes;                           // nNodes
    float* rinv    = t + nNodes;                           // nNodes
    int*   count   = (int*)(rinv + nNodes);                // nNodes
    int*   offsets = count + nNodes;                       // nNodes+1 (+pad)
    int*   bsum    = offsets + nNodes + 4;                 // NB
    int*   bscan   = bsum + NB;                            // NB
    int*   rank    = bscan + NB;                           // E
    int*   sdst    = rank + E;                             // E

    hipMemsetAsync(count, 0, (size_t)nNodes * sizeof(int), stream);

    fc_kernel<<<NBfc, 256, 0, stream>>>(x, W, aw, h, s, t, nNodes);
    hist_kernel<<<2048, 256, 0, stream>>>(ei, E, count, rank);
    scanA_kernel<<<NB, 256, 0, stream>>>(count, bsum, nNodes);
    scanB_kernel<<<1, 256, 0, stream>>>(bsum, bscan, NB);
    scanC_kernel<<<NB, 256, 0, stream>>>(count, bscan, offsets, nNodes);
    scatter_kernel<<<2048, 256, 0, stream>>>(ei, rank, offsets, E, sdst);
    agg_kernel<<<2048, 256, 0, stream>>>(offsets, sdst, s, t, h, ab,
                                         out, rinv, nNodes);
    alpha_kernel<<<2048, 256, 0, stream>>>(ei, s, t, rinv, ab, alpha, E);
}